// Round 1
// baseline (3201.976 us; speedup 1.0000x reference)
//
#include <hip/hip_runtime.h>

#define DEV __device__ __forceinline__

// ---- monotonic float<->uint mapping for atomic min on floats ----
DEV unsigned fmap_f(float f) {
    unsigned b = __float_as_uint(f);
    return (b & 0x80000000u) ? ~b : (b | 0x80000000u);
}
DEV float funmap_f(unsigned u) {
    return __uint_as_float((u & 0x80000000u) ? (u & 0x7fffffffu) : ~u);
}

// ---- scatter min over edges: agg[dst] = min(agg[dst], feat[src]) ----
template <int D>
__global__ __launch_bounds__(256) void scatter_min_k(
    const float* __restrict__ feat, const int* __restrict__ src,
    const int* __restrict__ dst, unsigned* __restrict__ agg, int total) {
    int t = blockIdx.x * 256 + threadIdx.x;
    if (t >= total) return;
    int e = t / D;
    int f = t - e * D;
    int s = src[e], d = dst[e];
    float v = feat[(size_t)s * D + f];
    atomicMin(&agg[(size_t)d * D + f], fmap_f(v));
}

// ---- unmap in place; sentinel (no in-edges) -> 0 ----
__global__ __launch_bounds__(256) void finalize_k(unsigned* agg, int total) {
    int t = blockIdx.x * 256 + threadIdx.x;
    if (t >= total) return;
    unsigned u = agg[t];
    ((float*)agg)[t] = (u == 0xFFFFFFFFu) ? 0.f : funmap_f(u);
}

// ---- out = agg @ wl + bl + h @ wr ; thread = (row, 4 cols) ----
template <int DIN, int DOUT>
__global__ __launch_bounds__(256) void linear_k(
    const float* __restrict__ agg, const float* __restrict__ h,
    const float* __restrict__ wl, const float* __restrict__ bl,
    const float* __restrict__ wr, float* __restrict__ out, int n) {
    constexpr int CT = DOUT / 4;
    constexpr int RT = 256 / CT;
    const int ct = threadIdx.x % CT;
    const int rt = threadIdx.x / CT;
    const int row = blockIdx.x * RT + rt;
    if (row >= n) return;
    const int col = ct * 4;
    const float* __restrict__ ar = agg + (size_t)row * DIN;
    const float* __restrict__ hr = h + (size_t)row * DIN;
    float4 acc = make_float4(0.f, 0.f, 0.f, 0.f);
#pragma unroll 4
    for (int k0 = 0; k0 < DIN; k0 += 4) {
        const float4 av = *(const float4*)(ar + k0);
        const float4 hv = *(const float4*)(hr + k0);
#pragma unroll
        for (int j = 0; j < 4; j++) {
            const float a = j == 0 ? av.x : j == 1 ? av.y : j == 2 ? av.z : av.w;
            const float b = j == 0 ? hv.x : j == 1 ? hv.y : j == 2 ? hv.z : hv.w;
            const float4 wlv = *(const float4*)(wl + (size_t)(k0 + j) * DOUT + col);
            const float4 wrv = *(const float4*)(wr + (size_t)(k0 + j) * DOUT + col);
            acc.x += a * wlv.x + b * wrv.x;
            acc.y += a * wlv.y + b * wrv.y;
            acc.z += a * wlv.z + b * wrv.z;
            acc.w += a * wlv.w + b * wrv.w;
        }
    }
    const float4 bv = *(const float4*)(bl + col);
    acc.x += bv.x; acc.y += bv.y; acc.z += bv.z; acc.w += bv.w;
    *(float4*)(out + (size_t)row * DOUT + col) = acc;
}

// ---- sh1 linear: inputs are concat([x(32), rm(3)]) parts ----
__global__ __launch_bounds__(256) void linear_sh_k(
    const float* __restrict__ aggx, const float* __restrict__ x,
    const float* __restrict__ aggr, const float* __restrict__ rm,
    const float* __restrict__ wl, const float* __restrict__ bl,
    const float* __restrict__ wr, float* __restrict__ out, int n) {
    constexpr int DOUT = 128, CT = 32, RT = 8;
    const int ct = threadIdx.x % CT;
    const int rt = threadIdx.x / CT;
    const int row = blockIdx.x * RT + rt;
    if (row >= n) return;
    const int col = ct * 4;
    const float* __restrict__ ar = aggx + (size_t)row * 32;
    const float* __restrict__ hr = x + (size_t)row * 32;
    float4 acc = make_float4(0.f, 0.f, 0.f, 0.f);
#pragma unroll 4
    for (int k0 = 0; k0 < 32; k0 += 4) {
        const float4 av = *(const float4*)(ar + k0);
        const float4 hv = *(const float4*)(hr + k0);
#pragma unroll
        for (int j = 0; j < 4; j++) {
            const float a = j == 0 ? av.x : j == 1 ? av.y : j == 2 ? av.z : av.w;
            const float b = j == 0 ? hv.x : j == 1 ? hv.y : j == 2 ? hv.z : hv.w;
            const float4 wlv = *(const float4*)(wl + (size_t)(k0 + j) * DOUT + col);
            const float4 wrv = *(const float4*)(wr + (size_t)(k0 + j) * DOUT + col);
            acc.x += a * wlv.x + b * wrv.x;
            acc.y += a * wlv.y + b * wrv.y;
            acc.z += a * wlv.z + b * wrv.z;
            acc.w += a * wlv.w + b * wrv.w;
        }
    }
#pragma unroll
    for (int k = 0; k < 3; k++) {
        const float a = aggr[(size_t)row * 3 + k];
        const float b = rm[(size_t)row * 3 + k];
        const float4 wlv = *(const float4*)(wl + (size_t)(32 + k) * DOUT + col);
        const float4 wrv = *(const float4*)(wr + (size_t)(32 + k) * DOUT + col);
        acc.x += a * wlv.x + b * wrv.x;
        acc.y += a * wlv.y + b * wrv.y;
        acc.z += a * wlv.z + b * wrv.z;
        acc.w += a * wlv.w + b * wrv.w;
    }
    const float4 bv = *(const float4*)(bl + col);
    acc.x += bv.x; acc.y += bv.y; acc.z += bv.z; acc.w += bv.w;
    *(float4*)(out + (size_t)row * DOUT + col) = acc;
}

// ---- per-column sum / sumsq (stride multiple of D => col fixed/thread) ----
template <int D>
__global__ __launch_bounds__(256) void colstats_k(
    const float* __restrict__ x, float* __restrict__ stats, int total) {
    int t0 = blockIdx.x * 256 + threadIdx.x;
    int stride = gridDim.x * 256;
    int col = t0 % D;
    float s = 0.f, s2 = 0.f;
    for (int t = t0; t < total; t += stride) {
        float v = x[t];
        s += v;
        s2 += v * v;
    }
    atomicAdd(&stats[col], s);
    atomicAdd(&stats[D + col], s2);
}

// ---- in-place BN (training stats) + ReLU ----
template <int D>
__global__ __launch_bounds__(256) void bnrelu_k(
    float* __restrict__ x, const float* __restrict__ stats,
    const float* __restrict__ g, const float* __restrict__ b, int total, float invN) {
    int t = blockIdx.x * 256 + threadIdx.x;
    if (t >= total) return;
    int col = t % D;
    float mu = stats[col] * invN;
    float var = stats[D + col] * invN - mu * mu;
    float sc = rsqrtf(var + 1e-5f) * g[col];
    float y = (x[t] - mu) * sc + b[col];
    x[t] = fmaxf(y, 0.f);
}

// ---- rm head: 64->3 linear, log_softmax, labels ----
__global__ __launch_bounds__(256) void rm_softmax_k(
    const float* __restrict__ agg, const float* __restrict__ h2,
    const float* __restrict__ wl, const float* __restrict__ bl,
    const float* __restrict__ wr, float* __restrict__ rm,
    float* __restrict__ ls_out, float* __restrict__ labels, int n) {
    int i = blockIdx.x * 256 + threadIdx.x;
    if (i >= n) return;
    const float* ar = agg + (size_t)i * 64;
    const float* hr = h2 + (size_t)i * 64;
    float r0 = bl[0], r1 = bl[1], r2 = bl[2];
#pragma unroll 8
    for (int k = 0; k < 64; k++) {
        float a = ar[k], hv = hr[k];
        r0 += a * wl[k * 3 + 0] + hv * wr[k * 3 + 0];
        r1 += a * wl[k * 3 + 1] + hv * wr[k * 3 + 1];
        r2 += a * wl[k * 3 + 2] + hv * wr[k * 3 + 2];
    }
    rm[i * 3 + 0] = r0; rm[i * 3 + 1] = r1; rm[i * 3 + 2] = r2;
    float m = fmaxf(r0, fmaxf(r1, r2));
    float s = expf(r0 - m) + expf(r1 - m) + expf(r2 - m);
    float lse = m + logf(s);
    ls_out[i * 3 + 0] = r0 - lse;
    ls_out[i * 3 + 1] = r1 - lse;
    ls_out[i * 3 + 2] = r2 - lse;
    // argmax (first-max tie rule) == 2  <=>  r2 strictly greater than r0 and r1
    labels[i] = (r2 > r0 && r2 > r1) ? 1.f : 0.f;
}

// ---- final heads: [N,64] @ [64,1] + b, masked by labels ----
__global__ __launch_bounds__(256) void final_k(
    const float* __restrict__ rth, const float* __restrict__ mdh,
    const float* __restrict__ rtw, const float* __restrict__ rtb,
    const float* __restrict__ mdw, const float* __restrict__ mdb,
    const float* __restrict__ lab, float* __restrict__ out_rt,
    float* __restrict__ out_md, int n) {
    int i = blockIdx.x * 256 + threadIdx.x;
    if (i >= n) return;
    const float* rr = rth + (size_t)i * 64;
    const float* mr = mdh + (size_t)i * 64;
    float a = rtb[0], b = mdb[0];
#pragma unroll 8
    for (int k = 0; k < 64; k++) {
        a += rr[k] * rtw[k];
        b += mr[k] * mdw[k];
    }
    float l = lab[i];
    out_rt[i] = a * l;
    out_md[i] = b * l;
}

extern "C" void kernel_launch(void* const* d_in, const int* in_sizes, int n_in,
                              void* d_out, int out_size, void* d_ws, size_t ws_size,
                              hipStream_t stream) {
    const float* x = (const float*)d_in[0];
    const int* ei = (const int*)d_in[1];
    const int E = in_sizes[1] / 2;
    const int n = in_sizes[0] / 32;
    const int* src = ei;
    const int* dst = ei + E;

    const float* rm1_wl = (const float*)d_in[2];
    const float* rm1_bl = (const float*)d_in[3];
    const float* rm1_wr = (const float*)d_in[4];
    const float* rmn1_g = (const float*)d_in[5];
    const float* rmn1_b = (const float*)d_in[6];
    const float* rm2_wl = (const float*)d_in[7];
    const float* rm2_bl = (const float*)d_in[8];
    const float* rm2_wr = (const float*)d_in[9];
    const float* rmn2_g = (const float*)d_in[10];
    const float* rmn2_b = (const float*)d_in[11];
    const float* rm4_wl = (const float*)d_in[12];
    const float* rm4_bl = (const float*)d_in[13];
    const float* rm4_wr = (const float*)d_in[14];
    const float* sh1_wl = (const float*)d_in[15];
    const float* sh1_bl = (const float*)d_in[16];
    const float* sh1_wr = (const float*)d_in[17];
    const float* shn1_g = (const float*)d_in[18];
    const float* shn1_b = (const float*)d_in[19];
    const float* rt1_wl = (const float*)d_in[20];
    const float* rt1_bl = (const float*)d_in[21];
    const float* rt1_wr = (const float*)d_in[22];
    const float* rtn1_g = (const float*)d_in[23];
    const float* rtn1_b = (const float*)d_in[24];
    const float* rt3_w = (const float*)d_in[25];
    const float* rt3_b = (const float*)d_in[26];
    const float* md1_wl = (const float*)d_in[27];
    const float* md1_bl = (const float*)d_in[28];
    const float* md1_wr = (const float*)d_in[29];
    const float* mdn1_g = (const float*)d_in[30];
    const float* mdn1_b = (const float*)d_in[31];
    const float* md3_w = (const float*)d_in[32];
    const float* md3_b = (const float*)d_in[33];

    // workspace layout
    char* w = (char*)d_ws;
    float* aggX = (float*)w; w += (size_t)n * 32 * 4;   // agg of x (uint then float)
    float* h1   = (float*)w; w += (size_t)n * 128 * 4;  // pre1/h1, later pre3/h3
    float* aggB = (float*)w; w += (size_t)n * 128 * 4;  // agg1, later agg3
    float* h2   = (float*)w; w += (size_t)n * 64 * 4;   // pre2/h2, later pre5/md_h
    float* aggM = (float*)w; w += (size_t)n * 64 * 4;   // agg2, later pre4/rt_h
    float* rmb  = (float*)w; w += (size_t)n * 3 * 4;
    float* aggR = (float*)w; w += (size_t)n * 3 * 4;
    float* lab  = (float*)w; w += (size_t)n * 4;
    float* stats = (float*)w; w += 256 * 4;

    float* out = (float*)d_out;
    float* out_ls = out;          // [n,3]
    float* out_rt = out + (size_t)3 * n;
    float* out_md = out + (size_t)4 * n;

    const float invN = 1.f / (float)n;
    auto cdiv = [](int a, int b) { return (a + b - 1) / b; };

    // ---- layer 1: sage(x, 32->128) + bn + relu -> h1
    hipMemsetAsync(aggX, 0xFF, (size_t)n * 32 * 4, stream);
    scatter_min_k<32><<<cdiv(E * 32, 256), 256, 0, stream>>>(x, src, dst, (unsigned*)aggX, E * 32);
    finalize_k<<<cdiv(n * 32, 256), 256, 0, stream>>>((unsigned*)aggX, n * 32);
    linear_k<32, 128><<<cdiv(n, 8), 256, 0, stream>>>(aggX, x, rm1_wl, rm1_bl, rm1_wr, h1, n);
    hipMemsetAsync(stats, 0, 256 * 4, stream);
    colstats_k<128><<<512, 256, 0, stream>>>(h1, stats, n * 128);
    bnrelu_k<128><<<cdiv(n * 128, 256), 256, 0, stream>>>(h1, stats, rmn1_g, rmn1_b, n * 128, invN);

    // ---- layer 2: sage(h1, 128->64) + bn + relu -> h2
    hipMemsetAsync(aggB, 0xFF, (size_t)n * 128 * 4, stream);
    scatter_min_k<128><<<cdiv(E * 128, 256), 256, 0, stream>>>(h1, src, dst, (unsigned*)aggB, E * 128);
    finalize_k<<<cdiv(n * 128, 256), 256, 0, stream>>>((unsigned*)aggB, n * 128);
    linear_k<128, 64><<<cdiv(n, 16), 256, 0, stream>>>(aggB, h1, rm2_wl, rm2_bl, rm2_wr, h2, n);
    hipMemsetAsync(stats, 0, 256 * 4, stream);
    colstats_k<64><<<512, 256, 0, stream>>>(h2, stats, n * 64);
    bnrelu_k<64><<<cdiv(n * 64, 256), 256, 0, stream>>>(h2, stats, rmn2_g, rmn2_b, n * 64, invN);

    // ---- rm head: sage(h2, 64->3), log_softmax, labels
    hipMemsetAsync(aggM, 0xFF, (size_t)n * 64 * 4, stream);
    scatter_min_k<64><<<cdiv(E * 64, 256), 256, 0, stream>>>(h2, src, dst, (unsigned*)aggM, E * 64);
    finalize_k<<<cdiv(n * 64, 256), 256, 0, stream>>>((unsigned*)aggM, n * 64);
    rm_softmax_k<<<cdiv(n, 256), 256, 0, stream>>>(aggM, h2, rm4_wl, rm4_bl, rm4_wr, rmb, out_ls, lab, n);

    // ---- sh1: sage([x,rm], 35->128) + bn + relu -> h3 (in h1 buffer)
    hipMemsetAsync(aggR, 0xFF, (size_t)n * 3 * 4, stream);
    scatter_min_k<3><<<cdiv(E * 3, 256), 256, 0, stream>>>(rmb, src, dst, (unsigned*)aggR, E * 3);
    finalize_k<<<cdiv(n * 3, 256), 256, 0, stream>>>((unsigned*)aggR, n * 3);
    linear_sh_k<<<cdiv(n, 8), 256, 0, stream>>>(aggX, x, aggR, rmb, sh1_wl, sh1_bl, sh1_wr, h1, n);
    hipMemsetAsync(stats, 0, 256 * 4, stream);
    colstats_k<128><<<512, 256, 0, stream>>>(h1, stats, n * 128);
    bnrelu_k<128><<<cdiv(n * 128, 256), 256, 0, stream>>>(h1, stats, shn1_g, shn1_b, n * 128, invN);

    // ---- shared aggregation of h3 for rt1 & md1
    hipMemsetAsync(aggB, 0xFF, (size_t)n * 128 * 4, stream);
    scatter_min_k<128><<<cdiv(E * 128, 256), 256, 0, stream>>>(h1, src, dst, (unsigned*)aggB, E * 128);
    finalize_k<<<cdiv(n * 128, 256), 256, 0, stream>>>((unsigned*)aggB, n * 128);

    // ---- rt branch: linear + bn + relu -> rt_h (in aggM buffer)
    linear_k<128, 64><<<cdiv(n, 16), 256, 0, stream>>>(aggB, h1, rt1_wl, rt1_bl, rt1_wr, aggM, n);
    hipMemsetAsync(stats, 0, 256 * 4, stream);
    colstats_k<64><<<512, 256, 0, stream>>>(aggM, stats, n * 64);
    bnrelu_k<64><<<cdiv(n * 64, 256), 256, 0, stream>>>(aggM, stats, rtn1_g, rtn1_b, n * 64, invN);

    // ---- md branch: linear + bn + relu -> md_h (in h2 buffer)
    linear_k<128, 64><<<cdiv(n, 16), 256, 0, stream>>>(aggB, h1, md1_wl, md1_bl, md1_wr, h2, n);
    hipMemsetAsync(stats, 0, 256 * 4, stream);
    colstats_k<64><<<512, 256, 0, stream>>>(h2, stats, n * 64);
    bnrelu_k<64><<<cdiv(n * 64, 256), 256, 0, stream>>>(h2, stats, mdn1_g, mdn1_b, n * 64, invN);

    // ---- final heads
    final_k<<<cdiv(n, 256), 256, 0, stream>>>(aggM, h2, rt3_w, rt3_b, md3_w, md3_b, lab,
                                              out_rt, out_md, n);
}

// Round 2
// 1470.037 us; speedup vs baseline: 2.1782x; 2.1782x over previous
//
#include <hip/hip_runtime.h>

#define FLTMAX 3.402823466e+38f

// ================= CSR build =================
__global__ __launch_bounds__(256) void hist_k(const int* __restrict__ dst,
                                              int* __restrict__ deg, int E) {
    int e = blockIdx.x * 256 + threadIdx.x;
    if (e >= E) return;
    atomicAdd(&deg[dst[e]], 1);
}

__global__ __launch_bounds__(256) void scan_block_k(const int* __restrict__ deg,
                                                    int* __restrict__ ptr,
                                                    int* __restrict__ bsum, int n) {
    __shared__ int ls[256];
    int i = blockIdx.x * 256 + threadIdx.x;
    int v = (i < n) ? deg[i] : 0;
    ls[threadIdx.x] = v;
    __syncthreads();
#pragma unroll
    for (int off = 1; off < 256; off <<= 1) {
        int a = (threadIdx.x >= off) ? ls[threadIdx.x - off] : 0;
        __syncthreads();
        ls[threadIdx.x] += a;
        __syncthreads();
    }
    if (i < n) ptr[i] = ls[threadIdx.x] - v;  // block-local exclusive
    if (threadIdx.x == 255) bsum[blockIdx.x] = ls[255];
}

__global__ __launch_bounds__(512) void scan_bsum_k(int* __restrict__ bsum, int nb) {
    __shared__ int ls[512];
    int t = threadIdx.x;
    int v = (t < nb) ? bsum[t] : 0;
    ls[t] = v;
    __syncthreads();
#pragma unroll
    for (int off = 1; off < 512; off <<= 1) {
        int a = (t >= off) ? ls[t - off] : 0;
        __syncthreads();
        ls[t] += a;
        __syncthreads();
    }
    if (t < nb) bsum[t] = ls[t] - v;  // exclusive
}

__global__ __launch_bounds__(256) void scan_add_k(int* __restrict__ ptr,
                                                  int* __restrict__ pos,
                                                  const int* __restrict__ bsum,
                                                  int n, int E) {
    int i = blockIdx.x * 256 + threadIdx.x;
    if (i == 0) ptr[n] = E;
    if (i < n) {
        int p = ptr[i] + bsum[blockIdx.x];
        ptr[i] = p;
        pos[i] = p;
    }
}

__global__ __launch_bounds__(256) void csr_fill_k(const int* __restrict__ src,
                                                  const int* __restrict__ dst,
                                                  int* __restrict__ pos,
                                                  int* __restrict__ csr, int E) {
    int e = blockIdx.x * 256 + threadIdx.x;
    if (e >= E) return;
    int p = atomicAdd(&pos[dst[e]], 1);
    csr[p] = src[e];
}

// ================= gather min (no atomics, finalize fused) =================
template <int D>
__global__ __launch_bounds__(256) void gather_min_k(
    const float* __restrict__ feat, const int* __restrict__ ptr,
    const int* __restrict__ csr, float* __restrict__ agg, int n) {
    constexpr int L = (D < 64) ? D : 64;  // lanes per node
    constexpr int NPW = 64 / L;           // nodes per wave
    constexpr int F = D / L;              // floats per lane
    const int lane = threadIdx.x & 63;
    const int wave = (blockIdx.x * 256 + threadIdx.x) >> 6;
    const int node = wave * NPW + lane / L;
    if (node >= n) return;
    const int fl = (lane % L) * F;
    int e = ptr[node];
    const int end = ptr[node + 1];
    const bool empty = (e == end);
    float m[F];
#pragma unroll
    for (int j = 0; j < F; j++) m[j] = FLTMAX;
    for (; e + 1 < end; e += 2) {  // 2 rows in flight
        const int s0 = csr[e], s1 = csr[e + 1];
        const float* r0 = feat + (size_t)s0 * D + fl;
        const float* r1 = feat + (size_t)s1 * D + fl;
        float v0[F], v1[F];
#pragma unroll
        for (int j = 0; j < F; j++) v0[j] = r0[j];
#pragma unroll
        for (int j = 0; j < F; j++) v1[j] = r1[j];
#pragma unroll
        for (int j = 0; j < F; j++) m[j] = fminf(m[j], fminf(v0[j], v1[j]));
    }
    if (e < end) {
        const float* r0 = feat + (size_t)csr[e] * D + fl;
#pragma unroll
        for (int j = 0; j < F; j++) m[j] = fminf(m[j], r0[j]);
    }
    float* o = agg + (size_t)node * D + fl;
#pragma unroll
    for (int j = 0; j < F; j++) o[j] = empty ? 0.f : m[j];
}

__global__ __launch_bounds__(256) void gather_min3_k(
    const float* __restrict__ feat, const int* __restrict__ ptr,
    const int* __restrict__ csr, float* __restrict__ agg, int n) {
    int i = blockIdx.x * 256 + threadIdx.x;
    if (i >= n) return;
    int e = ptr[i], end = ptr[i + 1];
    bool empty = (e == end);
    float m0 = FLTMAX, m1 = FLTMAX, m2 = FLTMAX;
    for (; e < end; e++) {
        const float* r = feat + (size_t)csr[e] * 3;
        m0 = fminf(m0, r[0]);
        m1 = fminf(m1, r[1]);
        m2 = fminf(m2, r[2]);
    }
    agg[(size_t)i * 3 + 0] = empty ? 0.f : m0;
    agg[(size_t)i * 3 + 1] = empty ? 0.f : m1;
    agg[(size_t)i * 3 + 2] = empty ? 0.f : m2;
}

// ====== out = agg @ wl + bl + h @ wr ; thread = 4 rows x 4 cols ======
template <int DIN, int DOUT>
__global__ __launch_bounds__(256) void linear4_k(
    const float* __restrict__ agg, const float* __restrict__ h,
    const float* __restrict__ wl, const float* __restrict__ bl,
    const float* __restrict__ wr, float* __restrict__ out, int n) {
    constexpr int CT = DOUT / 4;
    constexpr int RT = 256 / CT;
    constexpr int RB = RT * 4;
    const int ct = threadIdx.x % CT;
    const int rt = threadIdx.x / CT;
    const int col = ct * 4;
    const int row0 = blockIdx.x * RB + rt * 4;
    int r_idx[4];
#pragma unroll
    for (int r = 0; r < 4; r++) r_idx[r] = min(row0 + r, n - 1);
    float4 acc[4] = {};
#pragma unroll 2
    for (int k0 = 0; k0 < DIN; k0 += 4) {
        float4 wlv[4], wrv[4];
#pragma unroll
        for (int j = 0; j < 4; j++) {
            wlv[j] = *(const float4*)(wl + (size_t)(k0 + j) * DOUT + col);
            wrv[j] = *(const float4*)(wr + (size_t)(k0 + j) * DOUT + col);
        }
#pragma unroll
        for (int r = 0; r < 4; r++) {
            const float4 av = *(const float4*)(agg + (size_t)r_idx[r] * DIN + k0);
            const float4 hv = *(const float4*)(h + (size_t)r_idx[r] * DIN + k0);
            acc[r].x += av.x * wlv[0].x + hv.x * wrv[0].x;
            acc[r].y += av.x * wlv[0].y + hv.x * wrv[0].y;
            acc[r].z += av.x * wlv[0].z + hv.x * wrv[0].z;
            acc[r].w += av.x * wlv[0].w + hv.x * wrv[0].w;
            acc[r].x += av.y * wlv[1].x + hv.y * wrv[1].x;
            acc[r].y += av.y * wlv[1].y + hv.y * wrv[1].y;
            acc[r].z += av.y * wlv[1].z + hv.y * wrv[1].z;
            acc[r].w += av.y * wlv[1].w + hv.y * wrv[1].w;
            acc[r].x += av.z * wlv[2].x + hv.z * wrv[2].x;
            acc[r].y += av.z * wlv[2].y + hv.z * wrv[2].y;
            acc[r].z += av.z * wlv[2].z + hv.z * wrv[2].z;
            acc[r].w += av.z * wlv[2].w + hv.z * wrv[2].w;
            acc[r].x += av.w * wlv[3].x + hv.w * wrv[3].x;
            acc[r].y += av.w * wlv[3].y + hv.w * wrv[3].y;
            acc[r].z += av.w * wlv[3].z + hv.w * wrv[3].z;
            acc[r].w += av.w * wlv[3].w + hv.w * wrv[3].w;
        }
    }
    const float4 bv = *(const float4*)(bl + col);
#pragma unroll
    for (int r = 0; r < 4; r++) {
        if (row0 + r < n) {
            float4 o = acc[r];
            o.x += bv.x; o.y += bv.y; o.z += bv.z; o.w += bv.w;
            *(float4*)(out + (size_t)(row0 + r) * DOUT + col) = o;
        }
    }
}

// sh1: concat([x(32), rm(3)]) -> 128
__global__ __launch_bounds__(256) void linear_sh4_k(
    const float* __restrict__ aggx, const float* __restrict__ x,
    const float* __restrict__ aggr, const float* __restrict__ rm,
    const float* __restrict__ wl, const float* __restrict__ bl,
    const float* __restrict__ wr, float* __restrict__ out, int n) {
    constexpr int DOUT = 128, CT = 32, RT = 8, RB = RT * 4;
    const int ct = threadIdx.x % CT;
    const int rt = threadIdx.x / CT;
    const int col = ct * 4;
    const int row0 = blockIdx.x * RB + rt * 4;
    int r_idx[4];
#pragma unroll
    for (int r = 0; r < 4; r++) r_idx[r] = min(row0 + r, n - 1);
    float4 acc[4] = {};
#pragma unroll 2
    for (int k0 = 0; k0 < 32; k0 += 4) {
        float4 wlv[4], wrv[4];
#pragma unroll
        for (int j = 0; j < 4; j++) {
            wlv[j] = *(const float4*)(wl + (size_t)(k0 + j) * DOUT + col);
            wrv[j] = *(const float4*)(wr + (size_t)(k0 + j) * DOUT + col);
        }
#pragma unroll
        for (int r = 0; r < 4; r++) {
            const float4 av = *(const float4*)(aggx + (size_t)r_idx[r] * 32 + k0);
            const float4 hv = *(const float4*)(x + (size_t)r_idx[r] * 32 + k0);
            acc[r].x += av.x * wlv[0].x + hv.x * wrv[0].x;
            acc[r].y += av.x * wlv[0].y + hv.x * wrv[0].y;
            acc[r].z += av.x * wlv[0].z + hv.x * wrv[0].z;
            acc[r].w += av.x * wlv[0].w + hv.x * wrv[0].w;
            acc[r].x += av.y * wlv[1].x + hv.y * wrv[1].x;
            acc[r].y += av.y * wlv[1].y + hv.y * wrv[1].y;
            acc[r].z += av.y * wlv[1].z + hv.y * wrv[1].z;
            acc[r].w += av.y * wlv[1].w + hv.y * wrv[1].w;
            acc[r].x += av.z * wlv[2].x + hv.z * wrv[2].x;
            acc[r].y += av.z * wlv[2].y + hv.z * wrv[2].y;
            acc[r].z += av.z * wlv[2].z + hv.z * wrv[2].z;
            acc[r].w += av.z * wlv[2].w + hv.z * wrv[2].w;
            acc[r].x += av.w * wlv[3].x + hv.w * wrv[3].x;
            acc[r].y += av.w * wlv[3].y + hv.w * wrv[3].y;
            acc[r].z += av.w * wlv[3].z + hv.w * wrv[3].z;
            acc[r].w += av.w * wlv[3].w + hv.w * wrv[3].w;
        }
    }
#pragma unroll
    for (int k = 0; k < 3; k++) {
        const float4 wlv = *(const float4*)(wl + (size_t)(32 + k) * DOUT + col);
        const float4 wrv = *(const float4*)(wr + (size_t)(32 + k) * DOUT + col);
#pragma unroll
        for (int r = 0; r < 4; r++) {
            const float a = aggr[(size_t)r_idx[r] * 3 + k];
            const float b = rm[(size_t)r_idx[r] * 3 + k];
            acc[r].x += a * wlv.x + b * wrv.x;
            acc[r].y += a * wlv.y + b * wrv.y;
            acc[r].z += a * wlv.z + b * wrv.z;
            acc[r].w += a * wlv.w + b * wrv.w;
        }
    }
    const float4 bv = *(const float4*)(bl + col);
#pragma unroll
    for (int r = 0; r < 4; r++) {
        if (row0 + r < n) {
            float4 o = acc[r];
            o.x += bv.x; o.y += bv.y; o.z += bv.z; o.w += bv.w;
            *(float4*)(out + (size_t)(row0 + r) * DOUT + col) = o;
        }
    }
}

// ---- per-column sum / sumsq with LDS pre-reduction ----
template <int D>
__global__ __launch_bounds__(256) void colstats_k(
    const float* __restrict__ x, float* __restrict__ stats, int total) {
    __shared__ float ls[256];
    int t0 = blockIdx.x * 256 + threadIdx.x;
    int stride = gridDim.x * 256;
    float s = 0.f, s2 = 0.f;
    for (int t = t0; t < total; t += stride) {
        float v = x[t];
        s += v;
        s2 += v * v;
    }
    int col = threadIdx.x % D;
    ls[threadIdx.x] = s;
    __syncthreads();
    if (threadIdx.x < D) {
        float a = s;
        for (int u = threadIdx.x + D; u < 256; u += D) a += ls[u];
        atomicAdd(&stats[col], a);
    }
    __syncthreads();
    ls[threadIdx.x] = s2;
    __syncthreads();
    if (threadIdx.x < D) {
        float a = s2;
        for (int u = threadIdx.x + D; u < 256; u += D) a += ls[u];
        atomicAdd(&stats[D + col], a);
    }
}

// ---- in-place BN (training stats) + ReLU ----
template <int D>
__global__ __launch_bounds__(256) void bnrelu_k(
    float* __restrict__ x, const float* __restrict__ stats,
    const float* __restrict__ g, const float* __restrict__ b, int total, float invN) {
    int t = blockIdx.x * 256 + threadIdx.x;
    if (t >= total) return;
    int col = t % D;
    float mu = stats[col] * invN;
    float var = stats[D + col] * invN - mu * mu;
    float sc = rsqrtf(var + 1e-5f) * g[col];
    float y = (x[t] - mu) * sc + b[col];
    x[t] = fmaxf(y, 0.f);
}

// ---- rm head: 64->3 linear, log_softmax, labels ----
__global__ __launch_bounds__(256) void rm_softmax_k(
    const float* __restrict__ agg, const float* __restrict__ h2,
    const float* __restrict__ wl, const float* __restrict__ bl,
    const float* __restrict__ wr, float* __restrict__ rm,
    float* __restrict__ ls_out, float* __restrict__ labels, int n) {
    int i = blockIdx.x * 256 + threadIdx.x;
    if (i >= n) return;
    const float* ar = agg + (size_t)i * 64;
    const float* hr = h2 + (size_t)i * 64;
    float r0 = bl[0], r1 = bl[1], r2 = bl[2];
#pragma unroll 8
    for (int k = 0; k < 64; k++) {
        float a = ar[k], hv = hr[k];
        r0 += a * wl[k * 3 + 0] + hv * wr[k * 3 + 0];
        r1 += a * wl[k * 3 + 1] + hv * wr[k * 3 + 1];
        r2 += a * wl[k * 3 + 2] + hv * wr[k * 3 + 2];
    }
    rm[i * 3 + 0] = r0; rm[i * 3 + 1] = r1; rm[i * 3 + 2] = r2;
    float m = fmaxf(r0, fmaxf(r1, r2));
    float s = expf(r0 - m) + expf(r1 - m) + expf(r2 - m);
    float lse = m + logf(s);
    ls_out[i * 3 + 0] = r0 - lse;
    ls_out[i * 3 + 1] = r1 - lse;
    ls_out[i * 3 + 2] = r2 - lse;
    labels[i] = (r2 > r0 && r2 > r1) ? 1.f : 0.f;  // first-max argmax == 2
}

// ---- final heads: [N,64] @ [64,1] + b, masked by labels ----
__global__ __launch_bounds__(256) void final_k(
    const float* __restrict__ rth, const float* __restrict__ mdh,
    const float* __restrict__ rtw, const float* __restrict__ rtb,
    const float* __restrict__ mdw, const float* __restrict__ mdb,
    const float* __restrict__ lab, float* __restrict__ out_rt,
    float* __restrict__ out_md, int n) {
    int i = blockIdx.x * 256 + threadIdx.x;
    if (i >= n) return;
    const float* rr = rth + (size_t)i * 64;
    const float* mr = mdh + (size_t)i * 64;
    float a = rtb[0], b = mdb[0];
#pragma unroll 8
    for (int k = 0; k < 64; k++) {
        a += rr[k] * rtw[k];
        b += mr[k] * mdw[k];
    }
    float l = lab[i];
    out_rt[i] = a * l;
    out_md[i] = b * l;
}

extern "C" void kernel_launch(void* const* d_in, const int* in_sizes, int n_in,
                              void* d_out, int out_size, void* d_ws, size_t ws_size,
                              hipStream_t stream) {
    const float* x = (const float*)d_in[0];
    const int* ei = (const int*)d_in[1];
    const int E = in_sizes[1] / 2;
    const int n = in_sizes[0] / 32;
    const int* src = ei;
    const int* dst = ei + E;

    const float* rm1_wl = (const float*)d_in[2];
    const float* rm1_bl = (const float*)d_in[3];
    const float* rm1_wr = (const float*)d_in[4];
    const float* rmn1_g = (const float*)d_in[5];
    const float* rmn1_b = (const float*)d_in[6];
    const float* rm2_wl = (const float*)d_in[7];
    const float* rm2_bl = (const float*)d_in[8];
    const float* rm2_wr = (const float*)d_in[9];
    const float* rmn2_g = (const float*)d_in[10];
    const float* rmn2_b = (const float*)d_in[11];
    const float* rm4_wl = (const float*)d_in[12];
    const float* rm4_bl = (const float*)d_in[13];
    const float* rm4_wr = (const float*)d_in[14];
    const float* sh1_wl = (const float*)d_in[15];
    const float* sh1_bl = (const float*)d_in[16];
    const float* sh1_wr = (const float*)d_in[17];
    const float* shn1_g = (const float*)d_in[18];
    const float* shn1_b = (const float*)d_in[19];
    const float* rt1_wl = (const float*)d_in[20];
    const float* rt1_bl = (const float*)d_in[21];
    const float* rt1_wr = (const float*)d_in[22];
    const float* rtn1_g = (const float*)d_in[23];
    const float* rtn1_b = (const float*)d_in[24];
    const float* rt3_w = (const float*)d_in[25];
    const float* rt3_b = (const float*)d_in[26];
    const float* md1_wl = (const float*)d_in[27];
    const float* md1_bl = (const float*)d_in[28];
    const float* md1_wr = (const float*)d_in[29];
    const float* mdn1_g = (const float*)d_in[30];
    const float* mdn1_b = (const float*)d_in[31];
    const float* md3_w = (const float*)d_in[32];
    const float* md3_b = (const float*)d_in[33];

    // workspace layout
    char* w = (char*)d_ws;
    float* aggX = (float*)w; w += (size_t)n * 32 * 4;
    float* h1   = (float*)w; w += (size_t)n * 128 * 4;  // h1, later h3
    float* aggB = (float*)w; w += (size_t)n * 128 * 4;  // agg1, later agg3
    float* h2   = (float*)w; w += (size_t)n * 64 * 4;   // h2, later md_h
    float* aggM = (float*)w; w += (size_t)n * 64 * 4;   // agg2, later rt_h
    float* rmb  = (float*)w; w += (size_t)n * 3 * 4;
    float* aggR = (float*)w; w += (size_t)n * 3 * 4;
    float* lab  = (float*)w; w += (size_t)n * 4;
    float* stats = (float*)w; w += 256 * 4;
    int* ptr  = (int*)w; w += (size_t)(n + 1) * 4;
    int* pos  = (int*)w; w += (size_t)n * 4;
    int* bsum = (int*)w; w += 1024 * 4;
    int* csr  = (int*)w; w += (size_t)E * 4;

    float* out = (float*)d_out;
    float* out_ls = out;                    // [n,3]
    float* out_rt = out + (size_t)3 * n;
    float* out_md = out + (size_t)4 * n;

    const float invN = 1.f / (float)n;
    auto cdiv = [](int a, int b) { return (a + b - 1) / b; };
    const int nb = cdiv(n, 256);

    // ---- CSR build (once; graph shared by all 5 aggregations)
    hipMemsetAsync(pos, 0, (size_t)n * 4, stream);
    hist_k<<<cdiv(E, 256), 256, 0, stream>>>(dst, pos, E);
    scan_block_k<<<nb, 256, 0, stream>>>(pos, ptr, bsum, n);
    scan_bsum_k<<<1, 512, 0, stream>>>(bsum, nb);
    scan_add_k<<<nb, 256, 0, stream>>>(ptr, pos, bsum, n, E);
    csr_fill_k<<<cdiv(E, 256), 256, 0, stream>>>(src, dst, pos, csr, E);

    // ---- layer 1: sage(x, 32->128) + bn + relu -> h1
    gather_min_k<32><<<cdiv(cdiv(n, 2), 4), 256, 0, stream>>>(x, ptr, csr, aggX, n);
    linear4_k<32, 128><<<cdiv(n, 32), 256, 0, stream>>>(aggX, x, rm1_wl, rm1_bl, rm1_wr, h1, n);
    hipMemsetAsync(stats, 0, 256 * 4, stream);
    colstats_k<128><<<256, 256, 0, stream>>>(h1, stats, n * 128);
    bnrelu_k<128><<<cdiv(n * 128, 256), 256, 0, stream>>>(h1, stats, rmn1_g, rmn1_b, n * 128, invN);

    // ---- layer 2: sage(h1, 128->64) + bn + relu -> h2
    gather_min_k<128><<<cdiv(n, 4), 256, 0, stream>>>(h1, ptr, csr, aggB, n);
    linear4_k<128, 64><<<cdiv(n, 64), 256, 0, stream>>>(aggB, h1, rm2_wl, rm2_bl, rm2_wr, h2, n);
    hipMemsetAsync(stats, 0, 256 * 4, stream);
    colstats_k<64><<<256, 256, 0, stream>>>(h2, stats, n * 64);
    bnrelu_k<64><<<cdiv(n * 64, 256), 256, 0, stream>>>(h2, stats, rmn2_g, rmn2_b, n * 64, invN);

    // ---- rm head: sage(h2, 64->3), log_softmax, labels
    gather_min_k<64><<<cdiv(n, 4), 256, 0, stream>>>(h2, ptr, csr, aggM, n);
    rm_softmax_k<<<cdiv(n, 256), 256, 0, stream>>>(aggM, h2, rm4_wl, rm4_bl, rm4_wr, rmb, out_ls, lab, n);

    // ---- sh1: sage([x,rm], 35->128) + bn + relu -> h3 (in h1 buffer)
    gather_min3_k<<<cdiv(n, 256), 256, 0, stream>>>(rmb, ptr, csr, aggR, n);
    linear_sh4_k<<<cdiv(n, 32), 256, 0, stream>>>(aggX, x, aggR, rmb, sh1_wl, sh1_bl, sh1_wr, h1, n);
    hipMemsetAsync(stats, 0, 256 * 4, stream);
    colstats_k<128><<<256, 256, 0, stream>>>(h1, stats, n * 128);
    bnrelu_k<128><<<cdiv(n * 128, 256), 256, 0, stream>>>(h1, stats, shn1_g, shn1_b, n * 128, invN);

    // ---- shared aggregation of h3 for rt1 & md1
    gather_min_k<128><<<cdiv(n, 4), 256, 0, stream>>>(h1, ptr, csr, aggB, n);

    // ---- rt branch -> rt_h (in aggM buffer)
    linear4_k<128, 64><<<cdiv(n, 64), 256, 0, stream>>>(aggB, h1, rt1_wl, rt1_bl, rt1_wr, aggM, n);
    hipMemsetAsync(stats, 0, 256 * 4, stream);
    colstats_k<64><<<256, 256, 0, stream>>>(aggM, stats, n * 64);
    bnrelu_k<64><<<cdiv(n * 64, 256), 256, 0, stream>>>(aggM, stats, rtn1_g, rtn1_b, n * 64, invN);

    // ---- md branch -> md_h (in h2 buffer)
    linear4_k<128, 64><<<cdiv(n, 64), 256, 0, stream>>>(aggB, h1, md1_wl, md1_bl, md1_wr, h2, n);
    hipMemsetAsync(stats, 0, 256 * 4, stream);
    colstats_k<64><<<256, 256, 0, stream>>>(h2, stats, n * 64);
    bnrelu_k<64><<<cdiv(n * 64, 256), 256, 0, stream>>>(h2, stats, mdn1_g, mdn1_b, n * 64, invN);

    // ---- final heads
    final_k<<<cdiv(n, 256), 256, 0, stream>>>(aggM, h2, rt3_w, rt3_b, md3_w, md3_b, lab,
                                              out_rt, out_md, n);
}